// Round 2
// baseline (237.854 us; speedup 1.0000x reference)
//
#include <hip/hip_runtime.h>

#define HH 136
#define WW 240
#define HW (HH * WW)
#define DS 8
#define NQ (HW / 4)    // 8160 pixel-quads per (n, i) plane
#define QPR (WW / 4)   // 60 quads per coarse row (240 % 4 == 0: quad never spans rows)
#define OW (DS * WW)   // 1920
#define OH (DS * HH)   // 1088

typedef float vf4 __attribute__((ext_vector_type(4)));  // clang-native for nontemporal builtins

// One thread per (n, i, quad-of-4-pixels). Mask reads become 16 B/lane
// (global_load_dwordx4, 1 KB/wave-instruction) since consecutive pixels are
// contiguous within each mask channel plane. Output: 32 contiguous floats per
// channel per thread -> dense vf4 stores. j-loop split in halves of 4 to
// bound accumulator register pressure (~32 regs instead of 64).
__global__ __launch_bounds__(256) void upflow_kernel(
    const float* __restrict__ flow,
    const float* __restrict__ mask,
    float* __restrict__ out) {
  int q = blockIdx.x * 256 + threadIdx.x;
  if (q >= NQ) return;
  int ni = blockIdx.y;  // 0..31 = n*8 + i
  int i = ni & 7;
  int n = ni >> 3;
  int h = q / QPR;
  int w = (q - h * QPR) * 4;  // first pixel of the quad
  int p = h * WW + w;

  // Flow neighborhood for the quad: rows h-1..h+1, cols w-1..w+4,
  // both channels, pre-scaled by DS, zero-padded. L2-resident (~1 MB total).
  float f0[3][6], f1[3][6];
  const float* fb0 = flow + (size_t)(n * 2 + 0) * HW;
  const float* fb1 = flow + (size_t)(n * 2 + 1) * HW;
#pragma unroll
  for (int dy = 0; dy < 3; ++dy) {
    int hh = h + dy - 1;
    bool rok = (hh >= 0) && (hh < HH);
#pragma unroll
    for (int dx = 0; dx < 6; ++dx) {
      int cc = w + dx - 1;
      bool ok = rok && (cc >= 0) && (cc < WW);
      int idx = hh * WW + cc;
      f0[dy][dx] = ok ? 8.0f * fb0[idx] : 0.0f;
      f1[dy][dx] = ok ? 8.0f * fb1[idx] : 0.0f;
    }
  }

  // mask channel = k*64 + i*8 + j ; quad base p is 4-aligned -> 16 B aligned
  const float* mb = mask + (size_t)n * 576 * HW + (size_t)(i * 8) * HW + p;
  const float L2E = 1.4426950408889634f;

#pragma unroll
  for (int hj = 0; hj < 2; ++hj) {
    float a0[4][4], a1[4][4];  // [jj][pixel t]
#pragma unroll
    for (int jj = 0; jj < 4; ++jj) {
      const int j = hj * 4 + jj;
      float mk[9][4];
#pragma unroll
      for (int k = 0; k < 9; ++k) {
        vf4 v = __builtin_nontemporal_load(
            (const vf4*)(mb + (size_t)(k * 64 + j) * HW));
        mk[k][0] = v.x; mk[k][1] = v.y; mk[k][2] = v.z; mk[k][3] = v.w;
      }
      float mx[4], s[4], d0[4], d1[4];
#pragma unroll
      for (int t = 0; t < 4; ++t) {
        mx[t] = mk[0][t];
#pragma unroll
        for (int k = 1; k < 9; ++k) mx[t] = fmaxf(mx[t], mk[k][t]);
        s[t] = 0.0f; d0[t] = 0.0f; d1[t] = 0.0f;
      }
#pragma unroll
      for (int k = 0; k < 9; ++k) {
        const int dy = k / 3, dx = k % 3;
#pragma unroll
        for (int t = 0; t < 4; ++t) {
          float e = exp2f((mk[k][t] - mx[t]) * L2E);
          s[t] += e;
          d0[t] += e * f0[dy][t + dx];
          d1[t] += e * f1[dy][t + dx];
        }
      }
#pragma unroll
      for (int t = 0; t < 4; ++t) {
        float r = 1.0f / s[t];
        a0[jj][t] = d0[t] * r;
        a1[jj][t] = d1[t] * r;
      }
    }
    // out[n][c][h*8+i][(w+t)*8 + hj*4 + jj] ; vf4 along jj per pixel t
    size_t ob0 =
        ((size_t)(n * 2 + 0) * OH + (size_t)(h * 8 + i)) * OW + w * 8 + hj * 4;
    size_t ob1 = ob0 + (size_t)OH * OW;
#pragma unroll
    for (int t = 0; t < 4; ++t) {
      vf4 v0 = {a0[0][t], a0[1][t], a0[2][t], a0[3][t]};
      vf4 v1 = {a1[0][t], a1[1][t], a1[2][t], a1[3][t]};
      __builtin_nontemporal_store(v0, (vf4*)(out + ob0 + t * 8));
      __builtin_nontemporal_store(v1, (vf4*)(out + ob1 + t * 8));
    }
  }
}

extern "C" void kernel_launch(void* const* d_in, const int* in_sizes, int n_in,
                              void* d_out, int out_size, void* d_ws, size_t ws_size,
                              hipStream_t stream) {
  const float* flow = (const float*)d_in[0];
  const float* mask = (const float*)d_in[1];
  float* out = (float*)d_out;
  dim3 grid((NQ + 255) / 256, 32);  // y = n*8 + i
  upflow_kernel<<<grid, 256, 0, stream>>>(flow, mask, out);
}

// Round 3
// 96.913 us; speedup vs baseline: 2.4543x; 2.4543x over previous
//
#include <hip/hip_runtime.h>

#define HH 136
#define WW 240
#define HW (HH * WW)
#define DS 8
#define NQ (HW / 4)    // 8160 pixel-quads per (n, i) plane
#define QPR (WW / 4)   // 60 quads per coarse row (240 % 4 == 0: quad never spans rows)
#define OW (DS * WW)   // 1920
#define OH (DS * HH)   // 1088

typedef float vf4 __attribute__((ext_vector_type(4)));

// One thread per (n, i, quad-of-4-pixels). Mask reads are 16 B/lane
// (global_load_dwordx4, 1 KB/wave-instruction) since consecutive pixels are
// contiguous within each mask channel plane. Stores are plain (NOT
// nontemporal): the per-instruction lane scatter (16 B at 128 B stride) is
// merged into full lines by L2 byte-enables; nt stores bypassed that merge
// and inflated WRITE_SIZE 67->251 MB (R2 post-mortem).
__global__ __launch_bounds__(256) void upflow_kernel(
    const float* __restrict__ flow,
    const float* __restrict__ mask,
    float* __restrict__ out) {
  int q = blockIdx.x * 256 + threadIdx.x;
  if (q >= NQ) return;
  int ni = blockIdx.y;  // 0..31 = n*8 + i
  int i = ni & 7;
  int n = ni >> 3;
  int h = q / QPR;
  int w = (q - h * QPR) * 4;  // first pixel of the quad
  int p = h * WW + w;

  // Flow neighborhood for the quad: rows h-1..h+1, cols w-1..w+4,
  // both channels, pre-scaled by DS, zero-padded. L2/L3-resident (~1 MB).
  float f0[3][6], f1[3][6];
  const float* fb0 = flow + (size_t)(n * 2 + 0) * HW;
  const float* fb1 = flow + (size_t)(n * 2 + 1) * HW;
#pragma unroll
  for (int dy = 0; dy < 3; ++dy) {
    int hh = h + dy - 1;
    bool rok = (hh >= 0) && (hh < HH);
#pragma unroll
    for (int dx = 0; dx < 6; ++dx) {
      int cc = w + dx - 1;
      bool ok = rok && (cc >= 0) && (cc < WW);
      int idx = hh * WW + cc;
      f0[dy][dx] = ok ? 8.0f * fb0[idx] : 0.0f;
      f1[dy][dx] = ok ? 8.0f * fb1[idx] : 0.0f;
    }
  }

  // mask channel = k*64 + i*8 + j ; quad base p is 4-aligned -> 16 B aligned
  const float* mb = mask + (size_t)n * 576 * HW + (size_t)(i * 8) * HW + p;
  const float L2E = 1.4426950408889634f;

#pragma unroll
  for (int hj = 0; hj < 2; ++hj) {
    float a0[4][4], a1[4][4];  // [jj][pixel t]
#pragma unroll
    for (int jj = 0; jj < 4; ++jj) {
      const int j = hj * 4 + jj;
      float mk[9][4];
#pragma unroll
      for (int k = 0; k < 9; ++k) {
        vf4 v = *(const vf4*)(mb + (size_t)(k * 64 + j) * HW);
        mk[k][0] = v.x; mk[k][1] = v.y; mk[k][2] = v.z; mk[k][3] = v.w;
      }
      float mx[4], s[4], d0[4], d1[4];
#pragma unroll
      for (int t = 0; t < 4; ++t) {
        mx[t] = mk[0][t];
#pragma unroll
        for (int k = 1; k < 9; ++k) mx[t] = fmaxf(mx[t], mk[k][t]);
        s[t] = 0.0f; d0[t] = 0.0f; d1[t] = 0.0f;
      }
#pragma unroll
      for (int k = 0; k < 9; ++k) {
        const int dy = k / 3, dx = k % 3;
#pragma unroll
        for (int t = 0; t < 4; ++t) {
          float e = exp2f((mk[k][t] - mx[t]) * L2E);
          s[t] += e;
          d0[t] += e * f0[dy][t + dx];
          d1[t] += e * f1[dy][t + dx];
        }
      }
#pragma unroll
      for (int t = 0; t < 4; ++t) {
        float r = 1.0f / s[t];
        a0[jj][t] = d0[t] * r;
        a1[jj][t] = d1[t] * r;
      }
    }
    // out[n][c][h*8+i][(w+t)*8 + hj*4 + jj] ; vf4 along jj per pixel t
    size_t ob0 =
        ((size_t)(n * 2 + 0) * OH + (size_t)(h * 8 + i)) * OW + w * 8 + hj * 4;
    size_t ob1 = ob0 + (size_t)OH * OW;
#pragma unroll
    for (int t = 0; t < 4; ++t) {
      vf4 v0 = {a0[0][t], a0[1][t], a0[2][t], a0[3][t]};
      vf4 v1 = {a1[0][t], a1[1][t], a1[2][t], a1[3][t]};
      *(vf4*)(out + ob0 + t * 8) = v0;
      *(vf4*)(out + ob1 + t * 8) = v1;
    }
  }
}

extern "C" void kernel_launch(void* const* d_in, const int* in_sizes, int n_in,
                              void* d_out, int out_size, void* d_ws, size_t ws_size,
                              hipStream_t stream) {
  const float* flow = (const float*)d_in[0];
  const float* mask = (const float*)d_in[1];
  float* out = (float*)d_out;
  dim3 grid((NQ + 255) / 256, 32);  // y = n*8 + i
  upflow_kernel<<<grid, 256, 0, stream>>>(flow, mask, out);
}

// Round 4
// 90.472 us; speedup vs baseline: 2.6290x; 1.0712x over previous
//
#include <hip/hip_runtime.h>

#define HH 136
#define WW 240
#define HW (HH * WW)
#define DS 8
#define NP (HW / 2)    // 16320 pixel-pairs per (n, i) plane
#define PPR (WW / 2)   // 120 pairs per coarse row (pair never spans rows)
#define OW (DS * WW)   // 1920
#define OH (DS * HH)   // 1088

typedef float vf2 __attribute__((ext_vector_type(2)));
typedef float vf4 __attribute__((ext_vector_type(4)));

// One thread per (n, i, pixel-pair). Mask reads are 8 B/lane
// (global_load_dwordx2). All 8 j-outputs are computed before storing, so
// each channel's store is 4 back-to-back vf4 stores covering a fully
// contiguous 64 B per lane -> L2 merges full lines (R3 post-mortem: the
// hj-split quad layout left lines half-dirty across a long compute gap,
// WRITE_SIZE 140 MB vs ideal 67 MB). Pair granularity also doubles the
// wave count vs quads (8192 waves = full machine) to fix the 22%
// occupancy latency-bound signature.
__global__ __launch_bounds__(256) void upflow_kernel(
    const float* __restrict__ flow,
    const float* __restrict__ mask,
    float* __restrict__ out) {
  int q = blockIdx.x * 256 + threadIdx.x;
  if (q >= NP) return;
  int ni = blockIdx.y;  // 0..31 = n*8 + i
  int i = ni & 7;
  int n = ni >> 3;
  int h = q / PPR;
  int w = (q - h * PPR) * 2;  // first pixel of the pair
  int p = h * WW + w;

  // Flow neighborhood: rows h-1..h+1, cols w-1..w+2, both channels,
  // pre-scaled by DS, zero-padded. L2/L3-resident (~1 MB total).
  float f0[3][4], f1[3][4];
  const float* fb0 = flow + (size_t)(n * 2 + 0) * HW;
  const float* fb1 = flow + (size_t)(n * 2 + 1) * HW;
#pragma unroll
  for (int dy = 0; dy < 3; ++dy) {
    int hh = h + dy - 1;
    bool rok = (hh >= 0) && (hh < HH);
#pragma unroll
    for (int dx = 0; dx < 4; ++dx) {
      int cc = w + dx - 1;
      bool ok = rok && (cc >= 0) && (cc < WW);
      int idx = hh * WW + cc;
      f0[dy][dx] = ok ? 8.0f * fb0[idx] : 0.0f;
      f1[dy][dx] = ok ? 8.0f * fb1[idx] : 0.0f;
    }
  }

  // mask channel = k*64 + i*8 + j. Keep the lane-invariant channel offset in
  // uniform (SGPR) pointer arithmetic; p is the only lane-varying offset.
  const float* mbase = mask + (size_t)n * 576 * HW + (size_t)(i * 8) * HW;
  const float L2E = 1.4426950408889634f;

  float o0[8][2], o1[8][2];  // [j][pixel t]
#pragma unroll
  for (int j = 0; j < 8; ++j) {
    float mk[9][2];
#pragma unroll
    for (int k = 0; k < 9; ++k) {
      const float* cp = mbase + (size_t)(k * 64 + j) * HW;  // uniform
      vf2 v = *(const vf2*)(cp + p);                        // 8 B aligned
      mk[k][0] = v.x; mk[k][1] = v.y;
    }
#pragma unroll
    for (int t = 0; t < 2; ++t) {
      float mx = mk[0][t];
#pragma unroll
      for (int k = 1; k < 9; ++k) mx = fmaxf(mx, mk[k][t]);
      float s = 0.f, d0 = 0.f, d1 = 0.f;
#pragma unroll
      for (int k = 0; k < 9; ++k) {
        const int dy = k / 3, dx = k % 3;
        float e = exp2f((mk[k][t] - mx) * L2E);
        s += e;
        d0 += e * f0[dy][t + dx];
        d1 += e * f1[dy][t + dx];
      }
      float r = 1.0f / s;
      o0[j][t] = d0 * r;
      o1[j][t] = d1 * r;
    }
  }

  // out[n][c][h*8+i][(w+t)*8 + j] : 16 contiguous floats (64 B) per channel
  // per lane, written as 4 back-to-back vf4 stores.
  size_t ob0 = ((size_t)(n * 2 + 0) * OH + (size_t)(h * 8 + i)) * OW + w * 8;
  size_t ob1 = ob0 + (size_t)OH * OW;
  vf4 s00 = {o0[0][0], o0[1][0], o0[2][0], o0[3][0]};
  vf4 s01 = {o0[4][0], o0[5][0], o0[6][0], o0[7][0]};
  vf4 s02 = {o0[0][1], o0[1][1], o0[2][1], o0[3][1]};
  vf4 s03 = {o0[4][1], o0[5][1], o0[6][1], o0[7][1]};
  *(vf4*)(out + ob0) = s00;
  *(vf4*)(out + ob0 + 4) = s01;
  *(vf4*)(out + ob0 + 8) = s02;
  *(vf4*)(out + ob0 + 12) = s03;
  vf4 s10 = {o1[0][0], o1[1][0], o1[2][0], o1[3][0]};
  vf4 s11 = {o1[4][0], o1[5][0], o1[6][0], o1[7][0]};
  vf4 s12 = {o1[0][1], o1[1][1], o1[2][1], o1[3][1]};
  vf4 s13 = {o1[4][1], o1[5][1], o1[6][1], o1[7][1]};
  *(vf4*)(out + ob1) = s10;
  *(vf4*)(out + ob1 + 4) = s11;
  *(vf4*)(out + ob1 + 8) = s12;
  *(vf4*)(out + ob1 + 12) = s13;
}

extern "C" void kernel_launch(void* const* d_in, const int* in_sizes, int n_in,
                              void* d_out, int out_size, void* d_ws, size_t ws_size,
                              hipStream_t stream) {
  const float* flow = (const float*)d_in[0];
  const float* mask = (const float*)d_in[1];
  float* out = (float*)d_out;
  dim3 grid((NP + 255) / 256, 32);  // y = n*8 + i
  upflow_kernel<<<grid, 256, 0, stream>>>(flow, mask, out);
}